// Round 29
// baseline (87.335 us; speedup 1.0000x reference)
//
#include <hip/hip_runtime.h>

#define BB 4
#define MM 1024
#define NN 65536
#define CL (BB * MM)   // 4096 clusters
#define CAP 1024       // payload slots per cluster (64 MB total)

typedef float fvec4 __attribute__((ext_vector_type(4)));

#define ROTJ(APP, AQQ, APQ, ARP, ARQ, V0P, V1P, V2P, V0Q, V1Q, V2Q)            \
    do {                                                                       \
        double apq_ = APQ;                                                     \
        if (fabs(apq_) > 1e-300) {                                             \
            double theta_ = (AQQ - APP) / (2.0 * apq_);                        \
            double t_ = 1.0 / (fabs(theta_) + sqrt(theta_ * theta_ + 1.0));    \
            if (theta_ < 0.0) t_ = -t_;                                        \
            double c_ = 1.0 / sqrt(t_ * t_ + 1.0), sn_ = t_ * c_;              \
            APP -= t_ * apq_; AQQ += t_ * apq_; APQ = 0.0;                     \
            double arp_ = ARP, arq_ = ARQ;                                     \
            ARP = c_ * arp_ - sn_ * arq_;                                      \
            ARQ = sn_ * arp_ + c_ * arq_;                                      \
            double x_;                                                         \
            x_ = V0P; V0P = c_ * x_ - sn_ * V0Q; V0Q = sn_ * x_ + c_ * V0Q;    \
            x_ = V1P; V1P = c_ * x_ - sn_ * V1Q; V1Q = sn_ * x_ + c_ * V1Q;    \
            x_ = V2P; V2P = c_ * x_ - sn_ * V2Q; V2Q = sn_ * x_ + c_ * V2Q;    \
        }                                                                      \
    } while (0)

#define CESWAP(EI, EJ, VA, VB, VC, WA, WB, WC)                                 \
    do {                                                                       \
        if (EI < EJ) {                                                         \
            double tt_;                                                        \
            tt_ = EI; EI = EJ; EJ = tt_;                                       \
            tt_ = VA; VA = WA; WA = tt_;                                       \
            tt_ = VB; VB = WB; WB = tt_;                                       \
            tt_ = VC; VC = WC; WC = tt_;                                       \
        }                                                                      \
    } while (0)

// ---------------------------------------------------------------------------
// Kernel 0: clear cnt[] to 0 (16 KB).
// ---------------------------------------------------------------------------
__global__ __launch_bounds__(256) void k_clear_cnt(int4* __restrict__ cnt4)
{
    cnt4[blockIdx.x * 256 + threadIdx.x] = make_int4(0, 0, 0, 0);
}

// ---------------------------------------------------------------------------
// Kernel 1: argmin over M + scan-free bucket scatter with NONTEMPORAL stores
// (ext_vector_type so the builtin accepts it; bypasses L2 write-allocate,
// which caused R26's FETCH blow-up 1.75->3.38 GB and +20us).
// ---------------------------------------------------------------------------
__global__ __launch_bounds__(512) void k_assign(
    const float* __restrict__ pp, const float* __restrict__ smp,
    const float* __restrict__ nrm, int* __restrict__ cnt,
    fvec4* __restrict__ payload)
{
    __shared__ float4 pts[MM];          // 16 KB
    __shared__ float bestSh[8][256];    // 8 KB
    __shared__ int   biSh[8][256];      // 8 KB

    const int b   = blockIdx.x >> 8;    // 256 blocks per batch
    const int blk = blockIdx.x & 255;   // each block: 256 samples
    const float* P = pp + b * MM * 3;
    for (int i = threadIdx.x; i < MM; i += 512) {
        float x = P[i * 3 + 0], y = P[i * 3 + 1], z = P[i * 3 + 2];
        pts[i] = make_float4(x, y, z, x * x + y * y + z * z);
    }
    __syncthreads();

    const int l  = threadIdx.x & 63;
    const int g  = threadIdx.x >> 6;           // wave id = M-octant
    const int nb = blk * 256;
    const float* S = smp + (size_t)b * NN * 3;

    float ax[4], ay[4], az[4], best[4];
    int bi[4];
#pragma unroll
    for (int j = 0; j < 4; ++j) {
        int n = nb + j * 64 + l;
        ax[j] = -2.0f * S[n * 3 + 0];
        ay[j] = -2.0f * S[n * 3 + 1];
        az[j] = -2.0f * S[n * 3 + 2];
        best[j] = 3.4e38f;
        bi[j] = 0;
    }
    const int m0 = g * 128;
#pragma unroll 4
    for (int mi = 0; mi < 128; ++mi) {
        float4 p = pts[m0 + mi];
#pragma unroll
        for (int j = 0; j < 4; ++j) {
            float sc = fmaf(ax[j], p.x, fmaf(ay[j], p.y, fmaf(az[j], p.z, p.w)));
            if (sc < best[j]) { best[j] = sc; bi[j] = m0 + mi; }
        }
    }
#pragma unroll
    for (int j = 0; j < 4; ++j) {
        bestSh[g][j * 64 + l] = best[j];
        biSh[g][j * 64 + l]   = bi[j];
    }
    __syncthreads();

    if (threadIdx.x < 256) {
        const int t = threadIdx.x;             // sample slot in [0,256)
        float bb = bestSh[0][t];
        int   ii = biSh[0][t];
#pragma unroll
        for (int gg = 1; gg < 8; ++gg) {
            float bo = bestSh[gg][t];
            int   io = biSh[gg][t];
            if (bo < bb) { bb = bo; ii = io; } // tie -> lower g = lower m
        }
        const int n = nb + t;
        const int gc = b * MM + ii;            // global cluster id

        const float* Nr = nrm + (size_t)b * NN * 3;
        float sx = S[n * 3 + 0], sy = S[n * 3 + 1], sz = S[n * 3 + 2];
        float nx = Nr[n * 3 + 0], ny = Nr[n * 3 + 1], nz = Nr[n * 3 + 2];
        float d = -(nx * sx + ny * sy + nz * sz);
        fvec4 pl;
        pl[0] = nx; pl[1] = ny; pl[2] = nz; pl[3] = d;

        int pos = atomicAdd(&cnt[gc], 1);
        if (pos < CAP)
            __builtin_nontemporal_store(pl, &payload[((size_t)gc << 10) + pos]);
    }
}

// ---------------------------------------------------------------------------
// Kernel 2: per-cluster coalesced bucket reduce (wave per cluster) +
// SINGLE-THREAD fp64 Jacobi per cluster (threads 0..3 via LDS handoff).
// ---------------------------------------------------------------------------
__global__ __launch_bounds__(256) void k_cluster(
    const float* __restrict__ pp, const fvec4* __restrict__ payload,
    const int* __restrict__ cnt, float* __restrict__ out)
{
    __shared__ double sums[4][14];

    const int wid  = threadIdx.x >> 6;
    const int lane = threadIdx.x & 63;
    const int wave = blockIdx.x * 4 + wid;    // cluster id
    const int count = cnt[wave];
    const int stored = count < CAP ? count : CAP;
    const fvec4* PL = payload + ((size_t)wave << 10);

    double q00 = 0, q01 = 0, q02 = 0, q11 = 0, q12 = 0, q22 = 0;
    double nd0 = 0, nd1 = 0, nd2 = 0, s0 = 0, s1 = 0, s2 = 0;
    for (int i = lane; i < stored; i += 64) {
        fvec4 pl = PL[i];
        double nx = pl[0], ny = pl[1], nz = pl[2], d = pl[3];
        q00 += nx * nx; q01 += nx * ny; q02 += nx * nz;
        q11 += ny * ny; q12 += ny * nz; q22 += nz * nz;
        nd0 += nx * d; nd1 += ny * d; nd2 += nz * d;
        s0 += nx; s1 += ny; s2 += nz;
    }
#pragma unroll
    for (int o = 32; o > 0; o >>= 1) {
        q00 += __shfl_xor(q00, o); q01 += __shfl_xor(q01, o); q02 += __shfl_xor(q02, o);
        q11 += __shfl_xor(q11, o); q12 += __shfl_xor(q12, o); q22 += __shfl_xor(q22, o);
        nd0 += __shfl_xor(nd0, o); nd1 += __shfl_xor(nd1, o); nd2 += __shfl_xor(nd2, o);
        s0  += __shfl_xor(s0, o);  s1  += __shfl_xor(s1, o);  s2  += __shfl_xor(s2, o);
    }
    if (lane == 0) {
        sums[wid][0] = q00; sums[wid][1] = q01; sums[wid][2] = q02;
        sums[wid][3] = q11; sums[wid][4] = q12; sums[wid][5] = q22;
        sums[wid][6] = nd0; sums[wid][7] = nd1; sums[wid][8] = nd2;
        sums[wid][9] = s0;  sums[wid][10] = s1; sums[wid][11] = s2;
        sums[wid][12] = (double)count;
    }
    __syncthreads();

    if (threadIdx.x < 4) {
        const int c = blockIdx.x * 4 + threadIdx.x;   // cluster id
        const double* t = sums[threadIdx.x];
        const int cn = (int)t[12];

        double denom = cn > 1 ? (double)cn : 1.0;
        double A00 = t[0] / denom, A01 = t[1] / denom, A02 = t[2] / denom;
        double A11 = t[3] / denom, A12 = t[4] / denom, A22 = t[5] / denom;
        double bv0 = -t[6] / denom, bv1 = -t[7] / denom, bv2 = -t[8] / denom;
        double mn0 = t[9] / denom, mn1 = t[10] / denom, mn2 = t[11] / denom;
        bool nonvoid = (mn0 * mn0 + mn1 * mn1 + mn2 * mn2) > 0.0;

        double vs0 = 0, vs1 = 0, vs2 = 0;
        if (nonvoid) {
            double a00 = A00, a01 = A01, a02 = A02, a11 = A11, a12 = A12, a22 = A22;
            double v00 = 1, v01 = 0, v02 = 0;
            double v10 = 0, v11 = 1, v12 = 0;
            double v20 = 0, v21 = 0, v22 = 1;
#pragma unroll
            for (int sweep = 0; sweep < 8; ++sweep) {
                ROTJ(a00, a11, a01, a02, a12, v00, v10, v20, v01, v11, v21);
                ROTJ(a00, a22, a02, a01, a12, v00, v10, v20, v02, v12, v22);
                ROTJ(a11, a22, a12, a01, a02, v01, v11, v21, v02, v12, v22);
            }
            double e0 = a00, e1 = a11, e2 = a22;
            CESWAP(e0, e1, v00, v10, v20, v01, v11, v21);
            CESWAP(e0, e2, v00, v10, v20, v02, v12, v22);
            CESWAP(e1, e2, v01, v11, v21, v02, v12, v22);

            double emax = e0 > 1e-20 ? e0 : 1e-20;
            const float* Pp = pp + (size_t)c * 3;
            double px = Pp[0], py = Pp[1], pz = Pp[2];
            double r0 = bv0 - (A00 * px + A01 * py + A02 * pz);
            double r1 = bv1 - (A01 * px + A11 * py + A12 * pz);
            double r2 = bv2 - (A02 * px + A12 * py + A22 * pz);
            double thr = 0.01 * emax;
            if (e0 > thr) { double w = (v00 * r0 + v10 * r1 + v20 * r2) / e0; vs0 += w * v00; vs1 += w * v10; vs2 += w * v20; }
            if (e1 > thr) { double w = (v01 * r0 + v11 * r1 + v21 * r2) / e1; vs0 += w * v01; vs1 += w * v11; vs2 += w * v21; }
            if (e2 > thr) { double w = (v02 * r0 + v12 * r1 + v22 * r2) / e2; vs0 += w * v02; vs1 += w * v12; vs2 += w * v22; }
            vs0 += px; vs1 += py; vs2 += pz;
        }

        float* Ao = out + (size_t)c * 9;
        Ao[0] = (float)A00; Ao[1] = (float)A01; Ao[2] = (float)A02;
        Ao[3] = (float)A01; Ao[4] = (float)A11; Ao[5] = (float)A12;
        Ao[6] = (float)A02; Ao[7] = (float)A12; Ao[8] = (float)A22;
        float* Mo = out + 36864 + (size_t)c * 3;
        Mo[0] = (float)mn0; Mo[1] = (float)mn1; Mo[2] = (float)mn2;
        float* Vo = out + 49152 + (size_t)c * 3;
        Vo[0] = (float)vs0; Vo[1] = (float)vs1; Vo[2] = (float)vs2;
        out[61440 + c] = nonvoid ? 1.0f : 0.0f;
    }
}

// ---------------------------------------------------------------------------
extern "C" void kernel_launch(void* const* d_in, const int* in_sizes, int n_in,
                              void* d_out, int out_size, void* d_ws, size_t ws_size,
                              hipStream_t stream)
{
    const float* pp  = (const float*)d_in[0];   // (B,M,3)
    const float* smp = (const float*)d_in[1];   // (B,N,3)
    const float* nrm = (const float*)d_in[2];   // (B,N,3)
    float* out = (float*)d_out;

    int*   cnt     = (int*)d_ws;                         // CL ints (16 KB)
    fvec4* payload = (fvec4*)((char*)d_ws + 65536);      // CL*CAP fvec4 (64 MB)

    k_clear_cnt<<<4, 256, 0, stream>>>((int4*)cnt);
    k_assign<<<1024, 512, 0, stream>>>(pp, smp, nrm, cnt, payload);
    k_cluster<<<CL / 4, 256, 0, stream>>>(pp, payload, cnt, out);
}

// Round 30
// 71.109 us; speedup vs baseline: 1.2282x; 1.2282x over previous
//
#include <hip/hip_runtime.h>

#define BB 4
#define MM 1024
#define NN 65536
#define CL (BB * MM)   // 4096 clusters

// ---------------------------------------------------------------------------
// Kernel 0: clear head[] to -1 (custom; runtime fill kernel is slower).
// ---------------------------------------------------------------------------
__global__ __launch_bounds__(256) void k_clear(int4* __restrict__ head4)
{
    head4[blockIdx.x * 256 + threadIdx.x] = make_int4(-1, -1, -1, -1);
}

// ---------------------------------------------------------------------------
// Kernel 1: argmin over M + 64-way sublist insert (proven 40us, VALU-floor).
// 1024 blocks x 512 threads: 256 samples/block, K=4 samples/thread,
// split-M x8, 8-way LDS combine (strict-less ascending g = np first-min).
// ---------------------------------------------------------------------------
__global__ __launch_bounds__(512) void k_assign(
    const float* __restrict__ pp, const float* __restrict__ smp,
    int* __restrict__ head, int* __restrict__ next)
{
    __shared__ float4 pts[MM];          // 16 KB
    __shared__ float bestSh[8][256];    // 8 KB
    __shared__ int   biSh[8][256];      // 8 KB

    const int b   = blockIdx.x >> 8;    // 256 blocks per batch
    const int blk = blockIdx.x & 255;   // each block: 256 samples
    const float* P = pp + b * MM * 3;
    for (int i = threadIdx.x; i < MM; i += 512) {
        float x = P[i * 3 + 0], y = P[i * 3 + 1], z = P[i * 3 + 2];
        pts[i] = make_float4(x, y, z, x * x + y * y + z * z);
    }
    __syncthreads();

    const int l  = threadIdx.x & 63;
    const int g  = threadIdx.x >> 6;           // wave id = M-octant
    const int nb = blk * 256;
    const float* S = smp + (size_t)b * NN * 3;

    float ax[4], ay[4], az[4], best[4];
    int bi[4];
#pragma unroll
    for (int j = 0; j < 4; ++j) {
        int n = nb + j * 64 + l;
        ax[j] = -2.0f * S[n * 3 + 0];
        ay[j] = -2.0f * S[n * 3 + 1];
        az[j] = -2.0f * S[n * 3 + 2];
        best[j] = 3.4e38f;
        bi[j] = 0;
    }
    const int m0 = g * 128;
#pragma unroll 4
    for (int mi = 0; mi < 128; ++mi) {
        float4 p = pts[m0 + mi];
#pragma unroll
        for (int j = 0; j < 4; ++j) {
            float sc = fmaf(ax[j], p.x, fmaf(ay[j], p.y, fmaf(az[j], p.z, p.w)));
            if (sc < best[j]) { best[j] = sc; bi[j] = m0 + mi; }
        }
    }
#pragma unroll
    for (int j = 0; j < 4; ++j) {
        bestSh[g][j * 64 + l] = best[j];
        biSh[g][j * 64 + l]   = bi[j];
    }
    __syncthreads();

    if (threadIdx.x < 256) {
        const int t = threadIdx.x;             // sample slot in [0,256)
        float bb = bestSh[0][t];
        int   ii = biSh[0][t];
#pragma unroll
        for (int gg = 1; gg < 8; ++gg) {
            float bo = bestSh[gg][t];
            int   io = biSh[gg][t];
            if (bo < bb) { bb = bo; ii = io; } // tie -> lower g = lower m
        }
        const int n = nb + t;
        const int gc = b * MM + ii;            // global cluster id
        next[(size_t)b * NN + n] = atomicExch(&head[gc * 64 + (t & 63)], n);
    }
}

// ---------------------------------------------------------------------------
// Kernel 2: per-cluster (one wave each): all 64 lanes walk their own sublist
// concurrently, fp64 sums, shuffle-reduce, fp64 Jacobi, outputs.
// ---------------------------------------------------------------------------

#define ROTJ(APP, AQQ, APQ, ARP, ARQ, V0P, V1P, V2P, V0Q, V1Q, V2Q)            \
    do {                                                                       \
        double apq_ = APQ;                                                     \
        if (fabs(apq_) > 1e-300) {                                             \
            double theta_ = (AQQ - APP) / (2.0 * apq_);                        \
            double t_ = 1.0 / (fabs(theta_) + sqrt(theta_ * theta_ + 1.0));    \
            if (theta_ < 0.0) t_ = -t_;                                        \
            double c_ = 1.0 / sqrt(t_ * t_ + 1.0), sn_ = t_ * c_;              \
            APP -= t_ * apq_; AQQ += t_ * apq_; APQ = 0.0;                     \
            double arp_ = ARP, arq_ = ARQ;                                     \
            ARP = c_ * arp_ - sn_ * arq_;                                      \
            ARQ = sn_ * arp_ + c_ * arq_;                                      \
            double x_;                                                         \
            x_ = V0P; V0P = c_ * x_ - sn_ * V0Q; V0Q = sn_ * x_ + c_ * V0Q;    \
            x_ = V1P; V1P = c_ * x_ - sn_ * V1Q; V1Q = sn_ * x_ + c_ * V1Q;    \
            x_ = V2P; V2P = c_ * x_ - sn_ * V2Q; V2Q = sn_ * x_ + c_ * V2Q;    \
        }                                                                      \
    } while (0)

#define CESWAP(EI, EJ, VA, VB, VC, WA, WB, WC)                                 \
    do {                                                                       \
        if (EI < EJ) {                                                         \
            double tt_;                                                        \
            tt_ = EI; EI = EJ; EJ = tt_;                                       \
            tt_ = VA; VA = WA; WA = tt_;                                       \
            tt_ = VB; VB = WB; WB = tt_;                                       \
            tt_ = VC; VC = WC; WC = tt_;                                       \
        }                                                                      \
    } while (0)

__global__ __launch_bounds__(256) void k_cluster(
    const float* __restrict__ pp, const float* __restrict__ smp,
    const float* __restrict__ nrm, const int* __restrict__ head,
    const int* __restrict__ next, float* __restrict__ out)
{
    const int wave = blockIdx.x * 4 + (threadIdx.x >> 6);   // cluster id
    const int lane = threadIdx.x & 63;
    const int b = wave >> 10;
    const int* NX = next + (size_t)b * NN;
    const float* S  = smp + (size_t)b * NN * 3;
    const float* Nr = nrm + (size_t)b * NN * 3;

    double q00 = 0, q01 = 0, q02 = 0, q11 = 0, q12 = 0, q22 = 0;
    double nd0 = 0, nd1 = 0, nd2 = 0, s0 = 0, s1 = 0, s2 = 0;
    int count = 0;

    int cur = head[wave * 64 + lane];         // per-lane sublist head
    while (cur >= 0) {
        double sxv = S[cur * 3 + 0], syv = S[cur * 3 + 1], szv = S[cur * 3 + 2];
        double nx = Nr[cur * 3 + 0], ny = Nr[cur * 3 + 1], nz = Nr[cur * 3 + 2];
        double d = -(nx * sxv + ny * syv + nz * szv);
        q00 += nx * nx; q01 += nx * ny; q02 += nx * nz;
        q11 += ny * ny; q12 += ny * nz; q22 += nz * nz;
        nd0 += nx * d; nd1 += ny * d; nd2 += nz * d;
        s0 += nx; s1 += ny; s2 += nz;
        ++count;
        cur = NX[cur];
    }
#pragma unroll
    for (int o = 32; o > 0; o >>= 1) {
        q00 += __shfl_xor(q00, o); q01 += __shfl_xor(q01, o); q02 += __shfl_xor(q02, o);
        q11 += __shfl_xor(q11, o); q12 += __shfl_xor(q12, o); q22 += __shfl_xor(q22, o);
        nd0 += __shfl_xor(nd0, o); nd1 += __shfl_xor(nd1, o); nd2 += __shfl_xor(nd2, o);
        s0  += __shfl_xor(s0, o);  s1  += __shfl_xor(s1, o);  s2  += __shfl_xor(s2, o);
        count += __shfl_xor(count, o);
    }

    double denom = count > 1 ? (double)count : 1.0;
    double A00 = q00 / denom, A01 = q01 / denom, A02 = q02 / denom;
    double A11 = q11 / denom, A12 = q12 / denom, A22 = q22 / denom;
    double mn0 = s0 / denom, mn1 = s1 / denom, mn2 = s2 / denom;
    double bv0 = -nd0 / denom, bv1 = -nd1 / denom, bv2 = -nd2 / denom;
    bool nonvoid = (mn0 * mn0 + mn1 * mn1 + mn2 * mn2) > 0.0;

    double vs0 = 0, vs1 = 0, vs2 = 0;
    if (nonvoid) {
        double a00 = A00, a01 = A01, a02 = A02, a11 = A11, a12 = A12, a22 = A22;
        double v00 = 1, v01 = 0, v02 = 0;
        double v10 = 0, v11 = 1, v12 = 0;
        double v20 = 0, v21 = 0, v22 = 1;
#pragma unroll
        for (int sweep = 0; sweep < 8; ++sweep) {
            ROTJ(a00, a11, a01, a02, a12, v00, v10, v20, v01, v11, v21);
            ROTJ(a00, a22, a02, a01, a12, v00, v10, v20, v02, v12, v22);
            ROTJ(a11, a22, a12, a01, a02, v01, v11, v21, v02, v12, v22);
        }
        double e0 = a00, e1 = a11, e2 = a22;
        CESWAP(e0, e1, v00, v10, v20, v01, v11, v21);
        CESWAP(e0, e2, v00, v10, v20, v02, v12, v22);
        CESWAP(e1, e2, v01, v11, v21, v02, v12, v22);

        double emax = e0 > 1e-20 ? e0 : 1e-20;
        const float* Pp = pp + (size_t)wave * 3;
        double px = Pp[0], py = Pp[1], pz = Pp[2];
        double r0 = bv0 - (A00 * px + A01 * py + A02 * pz);
        double r1 = bv1 - (A01 * px + A11 * py + A12 * pz);
        double r2 = bv2 - (A02 * px + A12 * py + A22 * pz);
        double thr = 0.01 * emax;
        if (e0 > thr) { double w = (v00 * r0 + v10 * r1 + v20 * r2) / e0; vs0 += w * v00; vs1 += w * v10; vs2 += w * v20; }
        if (e1 > thr) { double w = (v01 * r0 + v11 * r1 + v21 * r2) / e1; vs0 += w * v01; vs1 += w * v11; vs2 += w * v21; }
        if (e2 > thr) { double w = (v02 * r0 + v12 * r1 + v22 * r2) / e2; vs0 += w * v02; vs1 += w * v12; vs2 += w * v22; }
        vs0 += px; vs1 += py; vs2 += pz;
    }

    if (lane == 0) {
        float* Ao = out + (size_t)wave * 9;
        Ao[0] = (float)A00; Ao[1] = (float)A01; Ao[2] = (float)A02;
        Ao[3] = (float)A01; Ao[4] = (float)A11; Ao[5] = (float)A12;
        Ao[6] = (float)A02; Ao[7] = (float)A12; Ao[8] = (float)A22;
        float* Mo = out + 36864 + (size_t)wave * 3;
        Mo[0] = (float)mn0; Mo[1] = (float)mn1; Mo[2] = (float)mn2;
        float* Vo = out + 49152 + (size_t)wave * 3;
        Vo[0] = (float)vs0; Vo[1] = (float)vs1; Vo[2] = (float)vs2;
        out[61440 + wave] = nonvoid ? 1.0f : 0.0f;
    }
}

// ---------------------------------------------------------------------------
extern "C" void kernel_launch(void* const* d_in, const int* in_sizes, int n_in,
                              void* d_out, int out_size, void* d_ws, size_t ws_size,
                              hipStream_t stream)
{
    const float* pp  = (const float*)d_in[0];   // (B,M,3)
    const float* smp = (const float*)d_in[1];   // (B,N,3)
    const float* nrm = (const float*)d_in[2];   // (B,N,3)
    float* out = (float*)d_out;

    int* head = (int*)d_ws;                     // CL*64 ints (1 MB)
    int* next = head + CL * 64;                 // B*N ints (1 MB)

    k_clear<<<256, 256, 0, stream>>>((int4*)head);
    k_assign<<<1024, 512, 0, stream>>>(pp, smp, head, next);
    k_cluster<<<CL / 4, 256, 0, stream>>>(pp, smp, nrm, head, next, out);
}